// Round 3
// baseline (3011.949 us; speedup 1.0000x reference)
//
#include <hip/hip_runtime.h>

#define N_NODES 100000
#define N_EDGES 600000
#define NPAD    100096      // 782 * 128
#define NTILES  782
#define SCAN_B  98          // ceil(100000/1024)
#define EPS_F   1e-5f

typedef __bf16 bf16_t;
typedef __bf16 bf16x8 __attribute__((ext_vector_type(8)));
typedef __bf16 bf16x4 __attribute__((ext_vector_type(4)));
typedef float  f32x4  __attribute__((ext_vector_type(4)));

// ---------------------------------------------------------------------------
// zero deg + stats
__global__ __launch_bounds__(256)
void init_zero_kernel(int* __restrict__ deg, float* __restrict__ stats)
{
    int i = blockIdx.x * 256 + threadIdx.x;
    if (i < N_NODES) deg[i] = 0;
    if (i < 9 * 768) stats[i] = 0.f;
}

// ---------------------------------------------------------------------------
// Weight pre-transpose: WT[mat][n][k] = W[mat][k][n], fp32 -> bf16.
__global__ __launch_bounds__(256)
void transpose_w_kernel(const float* __restrict__ Wz, const float* __restrict__ Wf,
                        const float* __restrict__ Wm, const float* __restrict__ Wl,
                        const float* __restrict__ Wc, bf16_t* __restrict__ wt)
{
    int idx = blockIdx.x * 256 + threadIdx.x;      // < 27*16384, exact grid
    int mat = idx >> 14;
    int off = idx & 16383;
    int n = off >> 7, kk = off & 127;
    const float* src;
    if      (mat < 3)  src = Wz + mat * 16384;
    else if (mat < 12) src = Wf + (mat - 3) * 16384;
    else if (mat < 18) src = Wm + (mat - 12) * 16384;
    else if (mat < 24) src = Wl + (mat - 18) * 16384;
    else               src = Wc + (mat - 24) * 16384;
    wt[idx] = (bf16_t)src[kk * 128 + n];
}

// ---------------------------------------------------------------------------
// pre-candidates, vectorized 8 elems/thread: [se, se-hr, se*hr] as bf16
__global__ __launch_bounds__(256)
void pre_kernel(const float* __restrict__ se, const float* __restrict__ hr,
                bf16_t* __restrict__ p0, bf16_t* __restrict__ p1, bf16_t* __restrict__ p2)
{
    long i = ((long)blockIdx.x * 256 + threadIdx.x) * 8;   // grid exact: N*128/2048
    float4 a0 = *(const float4*)&se[i], a1 = *(const float4*)&se[i + 4];
    float4 b0 = *(const float4*)&hr[i], b1 = *(const float4*)&hr[i + 4];
    float av[8] = {a0.x, a0.y, a0.z, a0.w, a1.x, a1.y, a1.z, a1.w};
    float bv[8] = {b0.x, b0.y, b0.z, b0.w, b1.x, b1.y, b1.z, b1.w};
    bf16x8 o0, o1, o2;
#pragma unroll
    for (int j = 0; j < 8; ++j) {
        o0[j] = (bf16_t)av[j];
        o1[j] = (bf16_t)(av[j] - bv[j]);
        o2[j] = (bf16_t)(av[j] * bv[j]);
    }
    *(bf16x8*)&p0[i] = o0;
    *(bf16x8*)&p1[i] = o1;
    *(bf16x8*)&p2[i] = o2;
}

// ---------------------------------------------------------------------------
// CSR build
__global__ __launch_bounds__(256)
void deg_count_kernel(const int* __restrict__ dst, int* __restrict__ deg)
{
    int i = blockIdx.x * 256 + threadIdx.x;
    if (i < N_EDGES) atomicAdd(&deg[dst[i]], 1);
}

__global__ __launch_bounds__(256)
void scan_a_kernel(const int* __restrict__ deg, int* __restrict__ partials)
{
    __shared__ int ls[256];
    int b = blockIdx.x, t = threadIdx.x;
    int s = 0;
    for (int j = 0; j < 4; ++j) {
        int i = b * 1024 + t * 4 + j;
        if (i < N_NODES) s += deg[i];
    }
    ls[t] = s; __syncthreads();
    for (int o = 128; o > 0; o >>= 1) {
        if (t < o) ls[t] += ls[t + o];
        __syncthreads();
    }
    if (t == 0) partials[b] = ls[0];
}

__global__ void scan_b_kernel(const int* __restrict__ partials, int* __restrict__ pofs)
{
    if (threadIdx.x == 0) {
        int a = 0;
        for (int i = 0; i < SCAN_B; ++i) { pofs[i] = a; a += partials[i]; }
    }
}

__global__ __launch_bounds__(256)
void scan_c_kernel(const int* __restrict__ deg, const int* __restrict__ pofs,
                   int* __restrict__ row_ptr, int* __restrict__ cursor)
{
    __shared__ int ls[256];
    int b = blockIdx.x, t = threadIdx.x;
    int v[4], s = 0;
    for (int j = 0; j < 4; ++j) {
        int i = b * 1024 + t * 4 + j;
        v[j] = (i < N_NODES) ? deg[i] : 0;
        s += v[j];
    }
    ls[t] = s; __syncthreads();
    for (int o = 1; o < 256; o <<= 1) {
        int tv = (t >= o) ? ls[t - o] : 0;
        __syncthreads();
        ls[t] += tv;
        __syncthreads();
    }
    int excl = ls[t] - s + pofs[b];
    for (int j = 0; j < 4; ++j) {
        int i = b * 1024 + t * 4 + j;
        if (i < N_NODES) { row_ptr[i] = excl; cursor[i] = excl; excl += v[j]; }
    }
    if (b == 0 && t == 0) row_ptr[N_NODES] = N_EDGES;
}

__global__ __launch_bounds__(256)
void scatter_kernel(const int* __restrict__ src, const int* __restrict__ dst,
                    int* __restrict__ cursor, int* __restrict__ csr_src)
{
    int i = blockIdx.x * 256 + threadIdx.x;
    if (i < N_EDGES) {
        int p = atomicAdd(&cursor[dst[i]], 1);
        csr_src[p] = src[i];
    }
}

// ---------------------------------------------------------------------------
// mean + max aggregation. 16 lanes per node, 16B loads per lane per edge.
__global__ __launch_bounds__(256)
void agg_kernel(const bf16_t* __restrict__ h, const int* __restrict__ row_ptr,
                const int* __restrict__ csr_src,
                bf16_t* __restrict__ mean_o, bf16_t* __restrict__ max_o)
{
    int node = blockIdx.x * 16 + (threadIdx.x >> 4);   // grid exact: N/16
    int dd = (threadIdx.x & 15) * 8;
    int e0 = row_ptr[node], e1 = row_ptr[node + 1];
    float s[8], mx[8];
#pragma unroll
    for (int j = 0; j < 8; ++j) { s[j] = 0.f; mx[j] = 0.f; }
    for (int e = e0; e < e1; ++e) {
        int sc = csr_src[e];
        bf16x8 v = *(const bf16x8*)&h[(long)sc * 128 + dd];
#pragma unroll
        for (int j = 0; j < 8; ++j) {
            float f = (float)v[j];
            s[j] += f;
            mx[j] = fmaxf(mx[j], f);
        }
    }
    float inv = 1.f / fmaxf((float)(e1 - e0), 1.f);
    bf16x8 om, ox;
#pragma unroll
    for (int j = 0; j < 8; ++j) { om[j] = (bf16_t)(s[j] * inv); ox[j] = (bf16_t)mx[j]; }
    *(bf16x8*)&mean_o[(long)node * 128 + dd] = om;
    *(bf16x8*)&max_o [(long)node * 128 + dd] = ox;
}

// ---------------------------------------------------------------------------
// GEMM: out = x @ W + b, bf16 in/out, fp32 MFMA acc. Fused stats epilogue:
// per-(feature) sum & sumsq over valid nodes -> atomicAdd into st.
// mode 0: grid.y = k (3 pairs, outputs y[k], stats st+k*256)
// mode 1: single output, accumulate over 3 k-chunks (cat, K=384), stats st.
__global__ __launch_bounds__(256, 2)
void gemm_kernel(const bf16_t* __restrict__ x0, const bf16_t* __restrict__ x1,
                 const bf16_t* __restrict__ x2, const bf16_t* __restrict__ wt,
                 const float* __restrict__ bias, bf16_t* __restrict__ out,
                 float* __restrict__ st, int mode)
{
    __shared__ bf16_t lds_w[16384];
    __shared__ bf16_t lds_x[16384];
    const int tid  = threadIdx.x;
    const int lane = tid & 63;
    const int wave = tid >> 6;
    const int quad = lane >> 4;
    const int t16  = lane & 15;
    const int wr = wave >> 1, wc = wave & 1;
    const long tile_base = (long)blockIdx.x * 128;

    f32x4 acc[4][4];
#pragma unroll
    for (int a = 0; a < 4; ++a)
#pragma unroll
        for (int b = 0; b < 4; ++b) acc[a][b] = (f32x4){0.f, 0.f, 0.f, 0.f};

    const int k_sel = blockIdx.y;
    const int nchunk = (mode == 0) ? 1 : 3;
    const bf16_t* xk = (k_sel == 0) ? x0 : ((k_sel == 1) ? x1 : x2);
    bf16_t* outp = (mode == 0) ? (out + (long)k_sel * NPAD * 128) : out;
    const float* bp = (mode == 0) ? (bias + k_sel * 128) : bias;
    float* stp = (mode == 0) ? (st + k_sel * 256) : st;

    for (int c3 = 0; c3 < nchunk; ++c3) {
        const bf16_t* xcur = (mode == 0) ? xk : ((c3 == 0) ? x0 : ((c3 == 1) ? x1 : x2));
        const bf16_t* wcur = (mode == 0) ? (wt + k_sel * 16384) : (wt + c3 * 16384);
        if (c3) __syncthreads();
#pragma unroll
        for (int i = 0; i < 8; ++i) {
            int idx = tid + i * 256;
            int row = idx >> 4, c = idx & 15;
            int sw = c ^ (row & 15);
            *(uint4*)&lds_w[row * 128 + sw * 8] = *(const uint4*)&wcur[row * 128 + c * 8];
            *(uint4*)&lds_x[row * 128 + sw * 8] = *(const uint4*)&xcur[(tile_base + row) * 128 + c * 8];
        }
        __syncthreads();
#pragma unroll
        for (int ks = 0; ks < 4; ++ks) {
            bf16x8 xf[4], wf[4];
#pragma unroll
            for (int ms = 0; ms < 4; ++ms) {
                int row = wr * 64 + ms * 16 + t16;
                int sw = (ks * 4 + quad) ^ t16;
                xf[ms] = *(const bf16x8*)&lds_x[row * 128 + sw * 8];
            }
#pragma unroll
            for (int ns = 0; ns < 4; ++ns) {
                int row = wc * 64 + ns * 16 + t16;
                int sw = (ks * 4 + quad) ^ t16;
                wf[ns] = *(const bf16x8*)&lds_w[row * 128 + sw * 8];
            }
#pragma unroll
            for (int ns = 0; ns < 4; ++ns)
#pragma unroll
                for (int ms = 0; ms < 4; ++ms)
                    acc[ns][ms] = __builtin_amdgcn_mfma_f32_16x16x32_bf16(
                        wf[ns], xf[ms], acc[ns][ms], 0, 0, 0);
        }
    }

    // epilogue: bias + store + per-feature (sum, sumsq) partials
    float ss[16], sq[16];
#pragma unroll
    for (int i = 0; i < 16; ++i) { ss[i] = 0.f; sq[i] = 0.f; }

#pragma unroll
    for (int ms = 0; ms < 4; ++ms) {
        long m = tile_base + wr * 64 + ms * 16 + t16;
        if (m < N_NODES) {
#pragma unroll
            for (int ns = 0; ns < 4; ++ns) {
                int n0 = wc * 64 + ns * 16 + quad * 4;
                float4 b4 = *(const float4*)&bp[n0];
                float v0 = acc[ns][ms][0] + b4.x;
                float v1 = acc[ns][ms][1] + b4.y;
                float v2 = acc[ns][ms][2] + b4.z;
                float v3 = acc[ns][ms][3] + b4.w;
                ss[ns * 4 + 0] += v0; sq[ns * 4 + 0] += v0 * v0;
                ss[ns * 4 + 1] += v1; sq[ns * 4 + 1] += v1 * v1;
                ss[ns * 4 + 2] += v2; sq[ns * 4 + 2] += v2 * v2;
                ss[ns * 4 + 3] += v3; sq[ns * 4 + 3] += v3 * v3;
                bf16x4 ov;
                ov[0] = (bf16_t)v0; ov[1] = (bf16_t)v1;
                ov[2] = (bf16_t)v2; ov[3] = (bf16_t)v3;
                *(bf16x4*)&outp[m * 128 + n0] = ov;
            }
        }
    }

    // reduce over the 16 lanes of each quad (xor masks < 16 stay in-quad)
#pragma unroll
    for (int o = 1; o < 16; o <<= 1) {
#pragma unroll
        for (int i = 0; i < 16; ++i) {
            ss[i] += __shfl_xor(ss[i], o);
            sq[i] += __shfl_xor(sq[i], o);
        }
    }
    if (t16 == 0) {
#pragma unroll
        for (int i = 0; i < 16; ++i) {
            int d = wc * 64 + (i >> 2) * 16 + quad * 4 + (i & 3);
            atomicAdd(&stp[d],       ss[i]);
            atomicAdd(&stp[128 + d], sq[i]);
        }
    }
}

// ---------------------------------------------------------------------------
// normalize + affine + relu + weighted sum over k -> state (bf16), 8 elem/thr
__global__ __launch_bounds__(256)
void passc_kernel(const bf16_t* __restrict__ y, const float* __restrict__ st,
                  const float* __restrict__ g, const float* __restrict__ be,
                  const float* __restrict__ w, bf16_t* __restrict__ out, int accflag)
{
    long base = ((long)blockIdx.x * 256 + threadIdx.x) * 8;   // grid: N*128/2048
    int d0 = (int)(base & 127);
    const float invN = 1.0f / (float)N_NODES;
    float res[8];
    if (accflag) {
        bf16x8 pv = *(const bf16x8*)&out[base];
#pragma unroll
        for (int j = 0; j < 8; ++j) res[j] = (float)pv[j];
    } else {
#pragma unroll
        for (int j = 0; j < 8; ++j) res[j] = 0.f;
    }
#pragma unroll
    for (int k = 0; k < 3; ++k) {
        bf16x8 yv = *(const bf16x8*)&y[(long)k * NPAD * 128 + base];
        float wk = w[k];
#pragma unroll
        for (int j = 0; j < 8; ++j) {
            int d = d0 + j;
            float mu  = st[k * 256 + d] * invN;
            float var = st[k * 256 + 128 + d] * invN - mu * mu;
            float rs  = rsqrtf(var + EPS_F);
            float v = ((float)yv[j] - mu) * rs * g[k * 128 + d] + be[k * 128 + d];
            res[j] += wk * fmaxf(v, 0.f);
        }
    }
    bf16x8 ov;
#pragma unroll
    for (int j = 0; j < 8; ++j) ov[j] = (bf16_t)res[j];
    *(bf16x8*)&out[base] = ov;
}

// ---------------------------------------------------------------------------
// final: out = relu((h - mu) * rsqrt(var+eps) * g + be), fp32 out, 8 elem/thr
__global__ __launch_bounds__(256)
void final_kernel(const bf16_t* __restrict__ h, const float* __restrict__ st,
                  const float* __restrict__ g, const float* __restrict__ be,
                  float* __restrict__ out)
{
    long base = ((long)blockIdx.x * 256 + threadIdx.x) * 8;
    int d0 = (int)(base & 127);
    const float invN = 1.0f / (float)N_NODES;
    bf16x8 hv = *(const bf16x8*)&h[base];
    float ov[8];
#pragma unroll
    for (int j = 0; j < 8; ++j) {
        int d = d0 + j;
        float mu  = st[d] * invN;
        float var = st[128 + d] * invN - mu * mu;
        float rs  = rsqrtf(var + EPS_F);
        float v = ((float)hv[j] - mu) * rs * g[d] + be[d];
        ov[j] = fmaxf(v, 0.f);
    }
    *(float4*)&out[base]     = (float4){ov[0], ov[1], ov[2], ov[3]};
    *(float4*)&out[base + 4] = (float4){ov[4], ov[5], ov[6], ov[7]};
}

// ---------------------------------------------------------------------------
extern "C" void kernel_launch(void* const* d_in, const int* in_sizes, int n_in,
                              void* d_out, int out_size, void* d_ws, size_t ws_size,
                              hipStream_t stream)
{
    const float* src_emb = (const float*)d_in[0];
    const float* hr      = (const float*)d_in[1];
    const int*   e_src   = (const int*)d_in[2];
    const int*   e_dst   = (const int*)d_in[3];
    const float* w_zero  = (const float*)d_in[4];
    const float* w_first = (const float*)d_in[5];
    const float* w_mid   = (const float*)d_in[6];
    const float* w_last  = (const float*)d_in[7];
    const float* W_zero  = (const float*)d_in[8];
    const float* b_zero  = (const float*)d_in[9];
    const float* g_zero  = (const float*)d_in[10];
    const float* be_zero = (const float*)d_in[11];
    const float* W_first = (const float*)d_in[12];
    const float* b_first = (const float*)d_in[13];
    const float* g_first = (const float*)d_in[14];
    const float* be_first= (const float*)d_in[15];
    const float* W_mid   = (const float*)d_in[16];
    const float* b_mid   = (const float*)d_in[17];
    const float* g_mid   = (const float*)d_in[18];
    const float* be_mid  = (const float*)d_in[19];
    const float* W_last  = (const float*)d_in[20];
    const float* b_last  = (const float*)d_in[21];
    const float* g_last  = (const float*)d_in[22];
    const float* be_last = (const float*)d_in[23];
    const float* W_cat   = (const float*)d_in[24];
    const float* b_cat   = (const float*)d_in[25];
    const float* g_cat   = (const float*)d_in[26];
    const float* be_cat  = (const float*)d_in[27];
    float* out = (float*)d_out;

    char* ws = (char*)d_ws;
    size_t off = 0;
    auto carve = [&](size_t bytes) -> char* {
        off = (off + 255) & ~(size_t)255;
        char* p = ws + off;
        off += bytes;
        return p;
    };

    const size_t SB = (size_t)NPAD * 128 * sizeof(bf16_t);
    bf16_t* B[8];
    for (int i = 0; i < 8; ++i) B[i] = (bf16_t*)carve(SB);
    bf16_t* ybuf = B[0];                 // B[0..2] double as the 3-slice y buffer
    bf16_t* wt    = (bf16_t*)carve((size_t)27 * 16384 * 2);
    float*  stats = (float*)carve(9 * 768 * sizeof(float));
    int* deg    = (int*)carve((size_t)N_NODES * 4);
    int* rowp   = (int*)carve((size_t)(N_NODES + 1) * 4);
    int* cursor = (int*)carve((size_t)N_NODES * 4);
    int* csr    = (int*)carve((size_t)N_EDGES * 4);
    int* parts  = (int*)carve(SCAN_B * 4);
    int* pofs   = (int*)carve(SCAN_B * 4);

    bf16_t* wtZ  = wt;
    bf16_t* wtF0 = wt + (size_t)3  * 16384;
    bf16_t* wtF1 = wt + (size_t)6  * 16384;
    bf16_t* wtF2 = wt + (size_t)9  * 16384;
    bf16_t* wtM0 = wt + (size_t)12 * 16384;
    bf16_t* wtM1 = wt + (size_t)15 * 16384;
    bf16_t* wtL0 = wt + (size_t)18 * 16384;
    bf16_t* wtL1 = wt + (size_t)21 * 16384;
    bf16_t* wtC  = wt + (size_t)24 * 16384;

    float* st0 = stats + 0 * 768;
    float* st1 = stats + 1 * 768;
    float* st2 = stats + 2 * 768;
    float* st3 = stats + 3 * 768;
    float* st4 = stats + 4 * 768;
    float* st5 = stats + 5 * 768;
    float* st6 = stats + 6 * 768;
    float* st7 = stats + 7 * 768;
    float* st8 = stats + 8 * 768;

    const int GEL8 = (N_NODES * 128) / 2048;   // 6250, exact

    init_zero_kernel<<<dim3((N_NODES + 255) / 256), dim3(256), 0, stream>>>(deg, stats);
    transpose_w_kernel<<<dim3(1728), dim3(256), 0, stream>>>(W_zero, W_first, W_mid, W_last, W_cat, wt);
    deg_count_kernel<<<dim3((N_EDGES + 255) / 256), dim3(256), 0, stream>>>(e_dst, deg);
    scan_a_kernel<<<dim3(SCAN_B), dim3(256), 0, stream>>>(deg, parts);
    scan_b_kernel<<<dim3(1), dim3(64), 0, stream>>>(parts, pofs);
    scan_c_kernel<<<dim3(SCAN_B), dim3(256), 0, stream>>>(deg, pofs, rowp, cursor);
    scatter_kernel<<<dim3((N_EDGES + 255) / 256), dim3(256), 0, stream>>>(e_src, e_dst, cursor, csr);

    auto G = [&](const bf16_t* x0_, const bf16_t* x1_, const bf16_t* x2_,
                 const bf16_t* w_, const float* b_, bf16_t* o_, float* st_, int mode) {
        gemm_kernel<<<dim3(NTILES, mode == 0 ? 3 : 1), dim3(256), 0, stream>>>(
            x0_, x1_, x2_, w_, b_, o_, st_, mode);
    };
    auto C = [&](const float* g_, const float* be_, const float* w_, float* st_,
                 bf16_t* o_, int acc) {
        passc_kernel<<<dim3(GEL8), dim3(256), 0, stream>>>(ybuf, st_, g_, be_, w_, o_, acc);
    };
    auto A = [&](const bf16_t* h_, bf16_t* me_, bf16_t* mx_) {
        agg_kernel<<<dim3(N_NODES / 16), dim3(256), 0, stream>>>(h_, rowp, csr, me_, mx_);
    };

    // zero op: pre -> B3,B4,B5 ; h_in = B6
    pre_kernel<<<dim3(GEL8), dim3(256), 0, stream>>>(src_emb, hr, B[3], B[4], B[5]);
    G(B[3], B[4], B[5], wtZ, b_zero, ybuf, st0, 0);
    C(g_zero, be_zero, w_zero, st0, B[6], 0);                        // h_in = B6

    A(B[6], B[3], B[4]);                                             // aggH -> B3,B4

    // s0 = mixed([h_in, aggH], first0)                              // s0 = B5
    G(B[6], B[3], B[4], wtF0, b_first + 0 * 384, ybuf, st1, 0);
    C(g_first + 0 * 384, be_first + 0 * 384, w_first + 0, st1, B[5], 0);

    // s1 (h_in contribution first, so h_in/aggH die early)          // s1 = B7
    G(B[6], B[3], B[4], wtF1, b_first + 1 * 384, ybuf, st2, 0);
    C(g_first + 1 * 384, be_first + 1 * 384, w_first + 3, st2, B[7], 0);
    // h_in(B6), aggH(B3,B4) dead

    A(B[5], B[3], B[4]);                                             // aggS0 -> B3,B4

    // s1 += mixed([s0, aggS0], first2)
    G(B[5], B[3], B[4], wtF2, b_first + 2 * 384, ybuf, st3, 0);
    C(g_first + 2 * 384, be_first + 2 * 384, w_first + 6, st3, B[7], 1);

    // m0 = mixed([s0, aggS0], mid0)                                 // m0 = B6
    G(B[5], B[3], B[4], wtM0, b_mid + 0 * 384, ybuf, st4, 0);
    C(g_mid + 0 * 384, be_mid + 0 * 384, w_mid + 0, st4, B[6], 0);
    // s0(B5), aggS0(B3,B4) dead

    A(B[7], B[3], B[4]);                                             // aggS1 -> B3,B4

    // m1 = mixed([s1, aggS1], mid1)                                 // m1 = B5
    G(B[7], B[3], B[4], wtM1, b_mid + 1 * 384, ybuf, st5, 0);
    C(g_mid + 1 * 384, be_mid + 1 * 384, w_mid + 3, st5, B[5], 0);
    // s1(B7), aggS1(B3,B4) dead

    // s_last = mixed([m0, agg m0], last0) + mixed([m1, agg m1], last1)  // sl = B7
    A(B[6], B[3], B[4]);
    G(B[6], B[3], B[4], wtL0, b_last + 0 * 384, ybuf, st6, 0);
    C(g_last + 0 * 384, be_last + 0 * 384, w_last + 0, st6, B[7], 0);
    A(B[5], B[3], B[4]);
    G(B[5], B[3], B[4], wtL1, b_last + 1 * 384, ybuf, st7, 0);
    C(g_last + 1 * 384, be_last + 1 * 384, w_last + 3, st7, B[7], 1);

    // h = [m0 | m1 | s_last] @ W_cat + b_cat  -> B0 (ybuf slot 0, dead)
    G(B[6], B[5], B[7], wtC, b_cat, B[0], st8, 1);
    final_kernel<<<dim3(GEL8), dim3(256), 0, stream>>>(B[0], st8, g_cat, be_cat, out);
}

// Round 4
// 1246.771 us; speedup vs baseline: 2.4158x; 2.4158x over previous
//
#include <hip/hip_runtime.h>

#define N_NODES 100000
#define N_EDGES 600000
#define NPAD    100096      // 782 * 128
#define NTILES  782
#define SCAN_B  98          // ceil(100000/1024)
#define EPS_F   1e-5f

typedef __bf16 bf16_t;
typedef __bf16 bf16x8 __attribute__((ext_vector_type(8)));
typedef __bf16 bf16x4 __attribute__((ext_vector_type(4)));
typedef float  f32x4  __attribute__((ext_vector_type(4)));

// ---------------------------------------------------------------------------
// zero deg + stats
__global__ __launch_bounds__(256)
void init_zero_kernel(int* __restrict__ deg, float* __restrict__ stats)
{
    int i = blockIdx.x * 256 + threadIdx.x;
    if (i < N_NODES) deg[i] = 0;
    if (i < 9 * 768) stats[i] = 0.f;
}

// ---------------------------------------------------------------------------
// Weight pre-transpose: WT[mat][n][k] = W[mat][k][n], fp32 -> bf16.
__global__ __launch_bounds__(256)
void transpose_w_kernel(const float* __restrict__ Wz, const float* __restrict__ Wf,
                        const float* __restrict__ Wm, const float* __restrict__ Wl,
                        const float* __restrict__ Wc, bf16_t* __restrict__ wt)
{
    int idx = blockIdx.x * 256 + threadIdx.x;      // < 27*16384, exact grid
    int mat = idx >> 14;
    int off = idx & 16383;
    int n = off >> 7, kk = off & 127;
    const float* src;
    if      (mat < 3)  src = Wz + mat * 16384;
    else if (mat < 12) src = Wf + (mat - 3) * 16384;
    else if (mat < 18) src = Wm + (mat - 12) * 16384;
    else if (mat < 24) src = Wl + (mat - 18) * 16384;
    else               src = Wc + (mat - 24) * 16384;
    wt[idx] = (bf16_t)src[kk * 128 + n];
}

// ---------------------------------------------------------------------------
// pre-candidates, vectorized 8 elems/thread: [se, se-hr, se*hr] as bf16
__global__ __launch_bounds__(256)
void pre_kernel(const float* __restrict__ se, const float* __restrict__ hr,
                bf16_t* __restrict__ p0, bf16_t* __restrict__ p1, bf16_t* __restrict__ p2)
{
    long i = ((long)blockIdx.x * 256 + threadIdx.x) * 8;   // grid exact: N*128/2048
    float4 a0 = *(const float4*)&se[i], a1 = *(const float4*)&se[i + 4];
    float4 b0 = *(const float4*)&hr[i], b1 = *(const float4*)&hr[i + 4];
    float av[8] = {a0.x, a0.y, a0.z, a0.w, a1.x, a1.y, a1.z, a1.w};
    float bv[8] = {b0.x, b0.y, b0.z, b0.w, b1.x, b1.y, b1.z, b1.w};
    bf16x8 o0, o1, o2;
#pragma unroll
    for (int j = 0; j < 8; ++j) {
        o0[j] = (bf16_t)av[j];
        o1[j] = (bf16_t)(av[j] - bv[j]);
        o2[j] = (bf16_t)(av[j] * bv[j]);
    }
    *(bf16x8*)&p0[i] = o0;
    *(bf16x8*)&p1[i] = o1;
    *(bf16x8*)&p2[i] = o2;
}

// ---------------------------------------------------------------------------
// CSR build
__global__ __launch_bounds__(256)
void deg_count_kernel(const int* __restrict__ dst, int* __restrict__ deg)
{
    int i = blockIdx.x * 256 + threadIdx.x;
    if (i < N_EDGES) atomicAdd(&deg[dst[i]], 1);
}

__global__ __launch_bounds__(256)
void scan_a_kernel(const int* __restrict__ deg, int* __restrict__ partials)
{
    __shared__ int ls[256];
    int b = blockIdx.x, t = threadIdx.x;
    int s = 0;
    for (int j = 0; j < 4; ++j) {
        int i = b * 1024 + t * 4 + j;
        if (i < N_NODES) s += deg[i];
    }
    ls[t] = s; __syncthreads();
    for (int o = 128; o > 0; o >>= 1) {
        if (t < o) ls[t] += ls[t + o];
        __syncthreads();
    }
    if (t == 0) partials[b] = ls[0];
}

__global__ void scan_b_kernel(const int* __restrict__ partials, int* __restrict__ pofs)
{
    if (threadIdx.x == 0) {
        int a = 0;
        for (int i = 0; i < SCAN_B; ++i) { pofs[i] = a; a += partials[i]; }
    }
}

__global__ __launch_bounds__(256)
void scan_c_kernel(const int* __restrict__ deg, const int* __restrict__ pofs,
                   int* __restrict__ row_ptr, int* __restrict__ cursor)
{
    __shared__ int ls[256];
    int b = blockIdx.x, t = threadIdx.x;
    int v[4], s = 0;
    for (int j = 0; j < 4; ++j) {
        int i = b * 1024 + t * 4 + j;
        v[j] = (i < N_NODES) ? deg[i] : 0;
        s += v[j];
    }
    ls[t] = s; __syncthreads();
    for (int o = 1; o < 256; o <<= 1) {
        int tv = (t >= o) ? ls[t - o] : 0;
        __syncthreads();
        ls[t] += tv;
        __syncthreads();
    }
    int excl = ls[t] - s + pofs[b];
    for (int j = 0; j < 4; ++j) {
        int i = b * 1024 + t * 4 + j;
        if (i < N_NODES) { row_ptr[i] = excl; cursor[i] = excl; excl += v[j]; }
    }
    if (b == 0 && t == 0) row_ptr[N_NODES] = N_EDGES;
}

__global__ __launch_bounds__(256)
void scatter_kernel(const int* __restrict__ src, const int* __restrict__ dst,
                    int* __restrict__ cursor, int* __restrict__ csr_src)
{
    int i = blockIdx.x * 256 + threadIdx.x;
    if (i < N_EDGES) {
        int p = atomicAdd(&cursor[dst[i]], 1);
        csr_src[p] = src[i];
    }
}

// ---------------------------------------------------------------------------
// mean + max aggregation. 16 lanes per node, 16B loads per lane per edge.
__global__ __launch_bounds__(256)
void agg_kernel(const bf16_t* __restrict__ h, const int* __restrict__ row_ptr,
                const int* __restrict__ csr_src,
                bf16_t* __restrict__ mean_o, bf16_t* __restrict__ max_o)
{
    int node = blockIdx.x * 16 + (threadIdx.x >> 4);   // grid exact: N/16
    int dd = (threadIdx.x & 15) * 8;
    int e0 = row_ptr[node], e1 = row_ptr[node + 1];
    float s[8], mx[8];
#pragma unroll
    for (int j = 0; j < 8; ++j) { s[j] = 0.f; mx[j] = 0.f; }
    for (int e = e0; e < e1; ++e) {
        int sc = csr_src[e];
        bf16x8 v = *(const bf16x8*)&h[(long)sc * 128 + dd];
#pragma unroll
        for (int j = 0; j < 8; ++j) {
            float f = (float)v[j];
            s[j] += f;
            mx[j] = fmaxf(mx[j], f);
        }
    }
    float inv = 1.f / fmaxf((float)(e1 - e0), 1.f);
    bf16x8 om, ox;
#pragma unroll
    for (int j = 0; j < 8; ++j) { om[j] = (bf16_t)(s[j] * inv); ox[j] = (bf16_t)mx[j]; }
    *(bf16x8*)&mean_o[(long)node * 128 + dd] = om;
    *(bf16x8*)&max_o [(long)node * 128 + dd] = ox;
}

// ---------------------------------------------------------------------------
// GEMM: out = x @ W + b, bf16 in/out, fp32 MFMA acc.
// Stats epilogue writes per-block partial (sum,sumsq) to a contention-free
// scratch array (NO hot atomics — R3 showed ~200cyc serialization per
// same-address atomic); a tiny reduce_stats kernel folds partials into st.
// mode 0: grid.y = k (3 pairs, outputs y[k]); mode 1: cat GEMM, K=384.
__global__ __launch_bounds__(256, 2)
void gemm_kernel(const bf16_t* __restrict__ x0, const bf16_t* __restrict__ x1,
                 const bf16_t* __restrict__ x2, const bf16_t* __restrict__ wt,
                 const float* __restrict__ bias, bf16_t* __restrict__ out,
                 float* __restrict__ partial, int mode)
{
    __shared__ bf16_t lds_w[16384];
    __shared__ bf16_t lds_x[16384];
    const int tid  = threadIdx.x;
    const int lane = tid & 63;
    const int wave = tid >> 6;
    const int quad = lane >> 4;
    const int t16  = lane & 15;
    const int wr = wave >> 1, wc = wave & 1;
    const long tile_base = (long)blockIdx.x * 128;

    f32x4 acc[4][4];
#pragma unroll
    for (int a = 0; a < 4; ++a)
#pragma unroll
        for (int b = 0; b < 4; ++b) acc[a][b] = (f32x4){0.f, 0.f, 0.f, 0.f};

    const int k_sel = blockIdx.y;
    const int nchunk = (mode == 0) ? 1 : 3;
    const bf16_t* xk = (k_sel == 0) ? x0 : ((k_sel == 1) ? x1 : x2);
    bf16_t* outp = (mode == 0) ? (out + (long)k_sel * NPAD * 128) : out;
    const float* bp = (mode == 0) ? (bias + k_sel * 128) : bias;

    for (int c3 = 0; c3 < nchunk; ++c3) {
        const bf16_t* xcur = (mode == 0) ? xk : ((c3 == 0) ? x0 : ((c3 == 1) ? x1 : x2));
        const bf16_t* wcur = (mode == 0) ? (wt + k_sel * 16384) : (wt + c3 * 16384);
        if (c3) __syncthreads();
#pragma unroll
        for (int i = 0; i < 8; ++i) {
            int idx = tid + i * 256;
            int row = idx >> 4, c = idx & 15;
            int sw = c ^ (row & 15);
            *(uint4*)&lds_w[row * 128 + sw * 8] = *(const uint4*)&wcur[row * 128 + c * 8];
            *(uint4*)&lds_x[row * 128 + sw * 8] = *(const uint4*)&xcur[(tile_base + row) * 128 + c * 8];
        }
        __syncthreads();
#pragma unroll
        for (int ks = 0; ks < 4; ++ks) {
            bf16x8 xf[4], wf[4];
#pragma unroll
            for (int ms = 0; ms < 4; ++ms) {
                int row = wr * 64 + ms * 16 + t16;
                int sw = (ks * 4 + quad) ^ t16;
                xf[ms] = *(const bf16x8*)&lds_x[row * 128 + sw * 8];
            }
#pragma unroll
            for (int ns = 0; ns < 4; ++ns) {
                int row = wc * 64 + ns * 16 + t16;
                int sw = (ks * 4 + quad) ^ t16;
                wf[ns] = *(const bf16x8*)&lds_w[row * 128 + sw * 8];
            }
#pragma unroll
            for (int ns = 0; ns < 4; ++ns)
#pragma unroll
                for (int ms = 0; ms < 4; ++ms)
                    acc[ns][ms] = __builtin_amdgcn_mfma_f32_16x16x32_bf16(
                        wf[ns], xf[ms], acc[ns][ms], 0, 0, 0);
        }
    }

    // epilogue: bias + store + per-feature (sum, sumsq) partials
    float ss[16], sq[16];
#pragma unroll
    for (int i = 0; i < 16; ++i) { ss[i] = 0.f; sq[i] = 0.f; }

#pragma unroll
    for (int ms = 0; ms < 4; ++ms) {
        long m = tile_base + wr * 64 + ms * 16 + t16;
        if (m < N_NODES) {
#pragma unroll
            for (int ns = 0; ns < 4; ++ns) {
                int n0 = wc * 64 + ns * 16 + quad * 4;
                float4 b4 = *(const float4*)&bp[n0];
                float v0 = acc[ns][ms][0] + b4.x;
                float v1 = acc[ns][ms][1] + b4.y;
                float v2 = acc[ns][ms][2] + b4.z;
                float v3 = acc[ns][ms][3] + b4.w;
                ss[ns * 4 + 0] += v0; sq[ns * 4 + 0] += v0 * v0;
                ss[ns * 4 + 1] += v1; sq[ns * 4 + 1] += v1 * v1;
                ss[ns * 4 + 2] += v2; sq[ns * 4 + 2] += v2 * v2;
                ss[ns * 4 + 3] += v3; sq[ns * 4 + 3] += v3 * v3;
                bf16x4 ov;
                ov[0] = (bf16_t)v0; ov[1] = (bf16_t)v1;
                ov[2] = (bf16_t)v2; ov[3] = (bf16_t)v3;
                *(bf16x4*)&outp[m * 128 + n0] = ov;
            }
        }
    }

    // in-quad-group reduction (xor masks < 16 stay within 16-lane groups)
#pragma unroll
    for (int o = 1; o < 16; o <<= 1) {
#pragma unroll
        for (int i = 0; i < 16; ++i) {
            ss[i] += __shfl_xor(ss[i], o);
            sq[i] += __shfl_xor(sq[i], o);
        }
    }

    // block combine via LDS (reuse lds_w storage), then ONE coalesced
    // 256-float store per block into partial[k][block][256].
    __syncthreads();                       // all MFMA LDS reads done
    float* lred = (float*)lds_w;           // 4 waves * 128 floats = 2KB
    if (t16 == 0) {
#pragma unroll
        for (int i = 0; i < 16; ++i) {
            lred[wave * 128 + quad * 32 + i]      = ss[i];
            lred[wave * 128 + quad * 32 + 16 + i] = sq[i];
        }
    }
    __syncthreads();
    {
        int t = tid;                       // t<128: sum of feature t; else sumsq
        int d   = t & 127;
        int sel = (t >> 7) * 16;           // 0 = ss, 16 = sq
        int dwc = d >> 6;
        int q   = (d >> 2) & 3;
        int i   = ((d >> 4) & 3) * 4 + (d & 3);
        float v = lred[(0 * 2 + dwc) * 128 + q * 32 + sel + i]
                + lred[(1 * 2 + dwc) * 128 + q * 32 + sel + i];
        long pidx = ((long)((mode == 0) ? k_sel : 0) * NTILES + blockIdx.x) * 256 + t;
        partial[pidx] = v;
    }
}

// ---------------------------------------------------------------------------
// fold partial[k][782][256] into st[k][256]; grid (nk, 8), 8 atomics/address.
__global__ __launch_bounds__(256)
void reduce_stats_kernel(const float* __restrict__ partial, float* __restrict__ st)
{
    int k = blockIdx.x, j = blockIdx.y, t = threadIdx.x;
    int b0 = j * 98, b1 = (b0 + 98 < NTILES) ? b0 + 98 : NTILES;
    float s = 0.f;
    const float* p = partial + (long)k * NTILES * 256 + t;
    for (int b = b0; b < b1; ++b) s += p[(long)b * 256];
    atomicAdd(&st[k * 256 + t], s);
}

// ---------------------------------------------------------------------------
// normalize + affine + relu + weighted sum over k -> state (bf16), 8 elem/thr
__global__ __launch_bounds__(256)
void passc_kernel(const bf16_t* __restrict__ y, const float* __restrict__ st,
                  const float* __restrict__ g, const float* __restrict__ be,
                  const float* __restrict__ w, bf16_t* __restrict__ out, int accflag)
{
    long base = ((long)blockIdx.x * 256 + threadIdx.x) * 8;   // grid: N*128/2048
    int d0 = (int)(base & 127);
    const float invN = 1.0f / (float)N_NODES;
    float res[8];
    if (accflag) {
        bf16x8 pv = *(const bf16x8*)&out[base];
#pragma unroll
        for (int j = 0; j < 8; ++j) res[j] = (float)pv[j];
    } else {
#pragma unroll
        for (int j = 0; j < 8; ++j) res[j] = 0.f;
    }
#pragma unroll
    for (int k = 0; k < 3; ++k) {
        bf16x8 yv = *(const bf16x8*)&y[(long)k * NPAD * 128 + base];
        float wk = w[k];
#pragma unroll
        for (int j = 0; j < 8; ++j) {
            int d = d0 + j;
            float mu  = st[k * 256 + d] * invN;
            float var = st[k * 256 + 128 + d] * invN - mu * mu;
            float rs  = rsqrtf(var + EPS_F);
            float v = ((float)yv[j] - mu) * rs * g[k * 128 + d] + be[k * 128 + d];
            res[j] += wk * fmaxf(v, 0.f);
        }
    }
    bf16x8 ov;
#pragma unroll
    for (int j = 0; j < 8; ++j) ov[j] = (bf16_t)res[j];
    *(bf16x8*)&out[base] = ov;
}

// ---------------------------------------------------------------------------
// final: out = relu((h - mu) * rsqrt(var+eps) * g + be), fp32 out, 8 elem/thr
__global__ __launch_bounds__(256)
void final_kernel(const bf16_t* __restrict__ h, const float* __restrict__ st,
                  const float* __restrict__ g, const float* __restrict__ be,
                  float* __restrict__ out)
{
    long base = ((long)blockIdx.x * 256 + threadIdx.x) * 8;
    int d0 = (int)(base & 127);
    const float invN = 1.0f / (float)N_NODES;
    bf16x8 hv = *(const bf16x8*)&h[base];
    float ov[8];
#pragma unroll
    for (int j = 0; j < 8; ++j) {
        int d = d0 + j;
        float mu  = st[d] * invN;
        float var = st[128 + d] * invN - mu * mu;
        float rs  = rsqrtf(var + EPS_F);
        float v = ((float)hv[j] - mu) * rs * g[d] + be[d];
        ov[j] = fmaxf(v, 0.f);
    }
    *(float4*)&out[base]     = (float4){ov[0], ov[1], ov[2], ov[3]};
    *(float4*)&out[base + 4] = (float4){ov[4], ov[5], ov[6], ov[7]};
}

// ---------------------------------------------------------------------------
extern "C" void kernel_launch(void* const* d_in, const int* in_sizes, int n_in,
                              void* d_out, int out_size, void* d_ws, size_t ws_size,
                              hipStream_t stream)
{
    const float* src_emb = (const float*)d_in[0];
    const float* hr      = (const float*)d_in[1];
    const int*   e_src   = (const int*)d_in[2];
    const int*   e_dst   = (const int*)d_in[3];
    const float* w_zero  = (const float*)d_in[4];
    const float* w_first = (const float*)d_in[5];
    const float* w_mid   = (const float*)d_in[6];
    const float* w_last  = (const float*)d_in[7];
    const float* W_zero  = (const float*)d_in[8];
    const float* b_zero  = (const float*)d_in[9];
    const float* g_zero  = (const float*)d_in[10];
    const float* be_zero = (const float*)d_in[11];
    const float* W_first = (const float*)d_in[12];
    const float* b_first = (const float*)d_in[13];
    const float* g_first = (const float*)d_in[14];
    const float* be_first= (const float*)d_in[15];
    const float* W_mid   = (const float*)d_in[16];
    const float* b_mid   = (const float*)d_in[17];
    const float* g_mid   = (const float*)d_in[18];
    const float* be_mid  = (const float*)d_in[19];
    const float* W_last  = (const float*)d_in[20];
    const float* b_last  = (const float*)d_in[21];
    const float* g_last  = (const float*)d_in[22];
    const float* be_last = (const float*)d_in[23];
    const float* W_cat   = (const float*)d_in[24];
    const float* b_cat   = (const float*)d_in[25];
    const float* g_cat   = (const float*)d_in[26];
    const float* be_cat  = (const float*)d_in[27];
    float* out = (float*)d_out;

    char* ws = (char*)d_ws;
    size_t off = 0;
    auto carve = [&](size_t bytes) -> char* {
        off = (off + 255) & ~(size_t)255;
        char* p = ws + off;
        off += bytes;
        return p;
    };

    const size_t SB = (size_t)NPAD * 128 * sizeof(bf16_t);
    bf16_t* B[8];
    for (int i = 0; i < 8; ++i) B[i] = (bf16_t*)carve(SB);
    bf16_t* ybuf = B[0];                 // B[0..2] double as the 3-slice y buffer
    bf16_t* wt    = (bf16_t*)carve((size_t)27 * 16384 * 2);
    float*  stats = (float*)carve(9 * 768 * sizeof(float));
    float*  partial = (float*)carve((size_t)3 * NTILES * 256 * sizeof(float));
    int* deg    = (int*)carve((size_t)N_NODES * 4);
    int* rowp   = (int*)carve((size_t)(N_NODES + 1) * 4);
    int* cursor = (int*)carve((size_t)N_NODES * 4);
    int* csr    = (int*)carve((size_t)N_EDGES * 4);
    int* parts  = (int*)carve(SCAN_B * 4);
    int* pofs   = (int*)carve(SCAN_B * 4);

    bf16_t* wtZ  = wt;
    bf16_t* wtF0 = wt + (size_t)3  * 16384;
    bf16_t* wtF1 = wt + (size_t)6  * 16384;
    bf16_t* wtF2 = wt + (size_t)9  * 16384;
    bf16_t* wtM0 = wt + (size_t)12 * 16384;
    bf16_t* wtM1 = wt + (size_t)15 * 16384;
    bf16_t* wtL0 = wt + (size_t)18 * 16384;
    bf16_t* wtL1 = wt + (size_t)21 * 16384;
    bf16_t* wtC  = wt + (size_t)24 * 16384;

    float* st0 = stats + 0 * 768;
    float* st1 = stats + 1 * 768;
    float* st2 = stats + 2 * 768;
    float* st3 = stats + 3 * 768;
    float* st4 = stats + 4 * 768;
    float* st5 = stats + 5 * 768;
    float* st6 = stats + 6 * 768;
    float* st7 = stats + 7 * 768;
    float* st8 = stats + 8 * 768;

    const int GEL8 = (N_NODES * 128) / 2048;   // 6250, exact

    init_zero_kernel<<<dim3((N_NODES + 255) / 256), dim3(256), 0, stream>>>(deg, stats);
    transpose_w_kernel<<<dim3(1728), dim3(256), 0, stream>>>(W_zero, W_first, W_mid, W_last, W_cat, wt);
    deg_count_kernel<<<dim3((N_EDGES + 255) / 256), dim3(256), 0, stream>>>(e_dst, deg);
    scan_a_kernel<<<dim3(SCAN_B), dim3(256), 0, stream>>>(deg, parts);
    scan_b_kernel<<<dim3(1), dim3(64), 0, stream>>>(parts, pofs);
    scan_c_kernel<<<dim3(SCAN_B), dim3(256), 0, stream>>>(deg, pofs, rowp, cursor);
    scatter_kernel<<<dim3((N_EDGES + 255) / 256), dim3(256), 0, stream>>>(e_src, e_dst, cursor, csr);

    // G: gemm + partial stats; immediately followed by reduce into st
    auto G = [&](const bf16_t* x0_, const bf16_t* x1_, const bf16_t* x2_,
                 const bf16_t* w_, const float* b_, bf16_t* o_, float* st_, int mode) {
        int nk = (mode == 0) ? 3 : 1;
        gemm_kernel<<<dim3(NTILES, nk), dim3(256), 0, stream>>>(
            x0_, x1_, x2_, w_, b_, o_, partial, mode);
        reduce_stats_kernel<<<dim3(nk, 8), dim3(256), 0, stream>>>(partial, st_);
    };
    auto C = [&](const float* g_, const float* be_, const float* w_, float* st_,
                 bf16_t* o_, int acc) {
        passc_kernel<<<dim3(GEL8), dim3(256), 0, stream>>>(ybuf, st_, g_, be_, w_, o_, acc);
    };
    auto A = [&](const bf16_t* h_, bf16_t* me_, bf16_t* mx_) {
        agg_kernel<<<dim3(N_NODES / 16), dim3(256), 0, stream>>>(h_, rowp, csr, me_, mx_);
    };

    // zero op: pre -> B3,B4,B5 ; h_in = B6
    pre_kernel<<<dim3(GEL8), dim3(256), 0, stream>>>(src_emb, hr, B[3], B[4], B[5]);
    G(B[3], B[4], B[5], wtZ, b_zero, ybuf, st0, 0);
    C(g_zero, be_zero, w_zero, st0, B[6], 0);                        // h_in = B6

    A(B[6], B[3], B[4]);                                             // aggH -> B3,B4

    // s0 = mixed([h_in, aggH], first0)                              // s0 = B5
    G(B[6], B[3], B[4], wtF0, b_first + 0 * 384, ybuf, st1, 0);
    C(g_first + 0 * 384, be_first + 0 * 384, w_first + 0, st1, B[5], 0);

    // s1 (h_in contribution first, so h_in/aggH die early)          // s1 = B7
    G(B[6], B[3], B[4], wtF1, b_first + 1 * 384, ybuf, st2, 0);
    C(g_first + 1 * 384, be_first + 1 * 384, w_first + 3, st2, B[7], 0);
    // h_in(B6), aggH(B3,B4) dead

    A(B[5], B[3], B[4]);                                             // aggS0 -> B3,B4

    // s1 += mixed([s0, aggS0], first2)
    G(B[5], B[3], B[4], wtF2, b_first + 2 * 384, ybuf, st3, 0);
    C(g_first + 2 * 384, be_first + 2 * 384, w_first + 6, st3, B[7], 1);

    // m0 = mixed([s0, aggS0], mid0)                                 // m0 = B6
    G(B[5], B[3], B[4], wtM0, b_mid + 0 * 384, ybuf, st4, 0);
    C(g_mid + 0 * 384, be_mid + 0 * 384, w_mid + 0, st4, B[6], 0);
    // s0(B5), aggS0(B3,B4) dead

    A(B[7], B[3], B[4]);                                             // aggS1 -> B3,B4

    // m1 = mixed([s1, aggS1], mid1)                                 // m1 = B5
    G(B[7], B[3], B[4], wtM1, b_mid + 1 * 384, ybuf, st5, 0);
    C(g_mid + 1 * 384, be_mid + 1 * 384, w_mid + 3, st5, B[5], 0);
    // s1(B7), aggS1(B3,B4) dead

    // s_last = mixed([m0, agg m0], last0) + mixed([m1, agg m1], last1)  // sl = B7
    A(B[6], B[3], B[4]);
    G(B[6], B[3], B[4], wtL0, b_last + 0 * 384, ybuf, st6, 0);
    C(g_last + 0 * 384, be_last + 0 * 384, w_last + 0, st6, B[7], 0);
    A(B[5], B[3], B[4]);
    G(B[5], B[3], B[4], wtL1, b_last + 1 * 384, ybuf, st7, 0);
    C(g_last + 1 * 384, be_last + 1 * 384, w_last + 3, st7, B[7], 1);

    // h = [m0 | m1 | s_last] @ W_cat + b_cat  -> B0 (ybuf slot 0, dead)
    G(B[6], B[5], B[7], wtC, b_cat, B[0], st8, 1);
    final_kernel<<<dim3(GEL8), dim3(256), 0, stream>>>(B[0], st8, g_cat, be_cat, out);
}